// Round 9
// baseline (107.138 us; speedup 1.0000x reference)
//
#include <hip/hip_runtime.h>
#include <math.h>

#define BB   256   // batch
#define OBS  256
#define HH   1024
#define AA   18

// clang-native packed f16: + -> v_pk_add_f16, elementwise_max -> v_pk_max_f16
typedef _Float16 h2 __attribute__((ext_vector_type(2)));

static __device__ __forceinline__ h2 u2h(unsigned int u) {
  return __builtin_bit_cast(h2, u);
}
static __device__ __forceinline__ unsigned int h2u(h2 v) {
  return __builtin_bit_cast(unsigned int, v);
}

// ---------------------------------------------------------------------------
// fc_in: h1pk[o/2][b] = pack_f16( x@W_in^T + b_in ) for o-pair
// grid (H/16, B/64), block 1024 = 8 k-splits x 2 o-octets. lane = b.
// x slice staged via LDS (f32, pitch 257). W_in rows wave-uniform -> s_load.
// (LDS 98 KB -> 1 block/CU regardless of VGPRs; no launch-bounds tweak.)
// ---------------------------------------------------------------------------
__global__ __launch_bounds__(1024) void fc_in_kernel(
    const float* __restrict__ x, const float* __restrict__ Wi,
    const float* __restrict__ bi, unsigned int* __restrict__ h1pk) {
  __shared__ float xs[64][OBS + 1];
  __shared__ float red[8][16][64];
  const int t    = threadIdx.x;
  const int lane = t & 63;
  const int wv   = __builtin_amdgcn_readfirstlane(t >> 6);
  const int oq   = wv & 1;
  const int s    = wv >> 1;        // k-split: 32 k each
  const int og   = blockIdx.x;
  const int bg   = blockIdx.y;
  const int o0   = og * 16 + oq * 8;
  const int k0   = s * 32;

  {
    const int row = t >> 4;          // 0..63
    const int c4  = t & 15;          // 0..15
    const float4* src = (const float4*)(x + (size_t)(bg * 64 + row) * OBS);
#pragma unroll
    for (int k = 0; k < 4; ++k) {
      const float4 v = src[c4 + 16 * k];
      const int col = (c4 + 16 * k) * 4;
      xs[row][col]     = v.x;
      xs[row][col + 1] = v.y;
      xs[row][col + 2] = v.z;
      xs[row][col + 3] = v.w;
    }
  }
  __syncthreads();

  const float* __restrict__ w0 = Wi + (size_t)(o0 + 0) * OBS + k0;
  const float* __restrict__ w1 = Wi + (size_t)(o0 + 1) * OBS + k0;
  const float* __restrict__ w2 = Wi + (size_t)(o0 + 2) * OBS + k0;
  const float* __restrict__ w3 = Wi + (size_t)(o0 + 3) * OBS + k0;
  const float* __restrict__ w4 = Wi + (size_t)(o0 + 4) * OBS + k0;
  const float* __restrict__ w5 = Wi + (size_t)(o0 + 5) * OBS + k0;
  const float* __restrict__ w6 = Wi + (size_t)(o0 + 6) * OBS + k0;
  const float* __restrict__ w7 = Wi + (size_t)(o0 + 7) * OBS + k0;

  float a0 = 0, a1 = 0, a2 = 0, a3 = 0, a4 = 0, a5 = 0, a6 = 0, a7 = 0;
#pragma unroll 8
  for (int k = 0; k < 32; ++k) {
    const float xv = xs[lane][k0 + k];
    a0 = fmaf(xv, w0[k], a0); a1 = fmaf(xv, w1[k], a1);
    a2 = fmaf(xv, w2[k], a2); a3 = fmaf(xv, w3[k], a3);
    a4 = fmaf(xv, w4[k], a4); a5 = fmaf(xv, w5[k], a5);
    a6 = fmaf(xv, w6[k], a6); a7 = fmaf(xv, w7[k], a7);
  }

  red[s][oq * 8 + 0][lane] = a0;  red[s][oq * 8 + 1][lane] = a1;
  red[s][oq * 8 + 2][lane] = a2;  red[s][oq * 8 + 3][lane] = a3;
  red[s][oq * 8 + 4][lane] = a4;  red[s][oq * 8 + 5][lane] = a5;
  red[s][oq * 8 + 6][lane] = a6;  red[s][oq * 8 + 7][lane] = a7;
  __syncthreads();

  if (t < 512) {
    const int op = t >> 6;
    const int bl = t & 63;
    float s0 = 0.f, s1 = 0.f;
#pragma unroll
    for (int ks = 0; ks < 8; ++ks) {
      s0 += red[ks][2 * op][bl];
      s1 += red[ks][2 * op + 1][bl];
    }
    s0 += bi[og * 16 + 2 * op];
    s1 += bi[og * 16 + 2 * op + 1];
    h2 p = {(_Float16)s0, (_Float16)s1};
    h1pk[(size_t)(og * 8 + op) * BB + bg * 64 + bl] = h2u(p);
  }
}

// ---------------------------------------------------------------------------
// mmplus v4 (packed f16): out[o][b] = OP_i( W[o][i] + h[i][b] )
// grid (H/8, B/64) = 512 blocks, block 1024 = 16 i-splits (64 i each).
// __launch_bounds__(1024, 8): 8 waves/EU = 32 waves/CU = 2 blocks/CU,
// forcing VGPR <= 64 so the LDS-shrink from v3 (16.4 KB) actually converts
// into doubled occupancy (hypothesis: v3 stayed at 1 block/CU on VGPRs).
// W f32 -> pk f16 into LDS in-flight (pitch 514, conflict-free b64 reads).
// Thread tile 2o x 4b. h coalesced dwordx4.
// ---------------------------------------------------------------------------
template <bool IS_MAX>
__global__ __launch_bounds__(1024, 8) void mmplus_kernel(
    const unsigned int* __restrict__ hpk,   // [H/2][B] dwords (i-pair, b)
    const float* __restrict__ Wf,           // [H][H] f32 (o, i)
    unsigned int* __restrict__ opk) {       // [H/2][B]
  constexpr int PITCH = 514;
  __shared__ __align__(16) unsigned int lds[8 * PITCH];  // 16.4 KB; red aliases
  const int t    = threadIdx.x;
  const int lane = t & 63;
  const int og2  = lane >> 4;      // o-pair group 0..3
  const int bq   = lane & 15;      // b-quad 0..15
  const int s    = __builtin_amdgcn_readfirstlane(t >> 6);  // i-split 0..15
  const int og   = blockIdx.x;     // 0..127, 8 o each
  const int bg   = blockIdx.y;

  // ---- stage W tile: 8 rows (two waves per row), f32 -> pk f16 ----
  {
    const int o_l = t >> 7;        // 0..7
    const int c   = t & 127;
    const float4* src = (const float4*)(Wf + (size_t)(og * 8 + o_l) * HH);
    unsigned int* dst = &lds[o_l * PITCH];
#pragma unroll
    for (int k = 0; k < 2; ++k) {
      const float4 v = src[c + 128 * k];
      h2 p0 = {(_Float16)v.x, (_Float16)v.y};
      h2 p1 = {(_Float16)v.z, (_Float16)v.w};
      *(uint2*)&dst[(c + 128 * k) * 2] = make_uint2(h2u(p0), h2u(p1));
    }
  }
  __syncthreads();

  const unsigned int* __restrict__ hp =
      hpk + (size_t)(s * 32) * BB + bg * 64 + bq * 4;
  const _Float16 INIT = (_Float16)(IS_MAX ? -65504.f : 65504.f);
  h2 acc[2][4];
#pragma unroll
  for (int j = 0; j < 2; ++j)
#pragma unroll
    for (int bb = 0; bb < 4; ++bb) acc[j][bb] = (h2){INIT, INIT};

  // 32 i-pairs for this split, 2 pairs (4 i) per iteration
#pragma unroll 4
  for (int it = 0; it < 16; ++it) {
    const int p = it * 2;
    const uint4 h0 = *(const uint4*)(hp + (size_t)p * BB);
    const uint4 h1 = *(const uint4*)(hp + (size_t)(p + 1) * BB);
    const h2 h0v[4] = {u2h(h0.x), u2h(h0.y), u2h(h0.z), u2h(h0.w)};
    const h2 h1v[4] = {u2h(h1.x), u2h(h1.y), u2h(h1.z), u2h(h1.w)};
#pragma unroll
    for (int j = 0; j < 2; ++j) {
      const uint2 wj = *(const uint2*)&lds[(og2 * 2 + j) * PITCH + s * 32 + p];
      const h2 wa = u2h(wj.x);
      const h2 wb = u2h(wj.y);
#pragma unroll
      for (int bb = 0; bb < 4; ++bb) {
        if (IS_MAX) {
          acc[j][bb] = __builtin_elementwise_max(acc[j][bb], wa + h0v[bb]);
          acc[j][bb] = __builtin_elementwise_max(acc[j][bb], wb + h1v[bb]);
        } else {
          acc[j][bb] = __builtin_elementwise_min(acc[j][bb], wa + h0v[bb]);
          acc[j][bb] = __builtin_elementwise_min(acc[j][bb], wb + h1v[bb]);
        }
      }
    }
  }

  // fold even/odd i-partials -> scalar f16 per (o,b); pack this thread's
  // o-pair (j=0 even row, j=1 odd row)
  unsigned int opack[4];
#pragma unroll
  for (int bb = 0; bb < 4; ++bb) {
    const h2 ae = acc[0][bb], ao = acc[1][bb];
    const _Float16 me = IS_MAX ? (ae.x > ae.y ? ae.x : ae.y)
                               : (ae.x < ae.y ? ae.x : ae.y);
    const _Float16 mo = IS_MAX ? (ao.x > ao.y ? ao.x : ao.y)
                               : (ao.x < ao.y ? ao.x : ao.y);
    opack[bb] = h2u((h2){me, mo});
  }

  __syncthreads();  // W reads done; reuse lds[] as red[16][4][64] (16 KB)
#pragma unroll
  for (int bb = 0; bb < 4; ++bb)
    lds[s * 256 + og2 * 64 + bq * 4 + bb] = opack[bb];
  __syncthreads();

  if (t < 256) {
    const int op = t >> 6;   // o-pair 0..3
    const int bl = t & 63;
    h2 m = u2h(lds[op * 64 + bl]);
#pragma unroll
    for (int ks = 1; ks < 16; ++ks) {
      const h2 v = u2h(lds[ks * 256 + op * 64 + bl]);
      m = IS_MAX ? __builtin_elementwise_max(m, v)
                 : __builtin_elementwise_min(m, v);
    }
    opk[(size_t)(og * 4 + op) * BB + bg * 64 + bl] = h2u(m);
  }
}

// ---------------------------------------------------------------------------
// fc_out: q[b][a] = bo[a] + dot(h3[:,b], W_out[a,:])
// grid (A, B/64), block 1024 = 16 k-splits x 64 b. (R5, unchanged.)
// ---------------------------------------------------------------------------
__global__ __launch_bounds__(1024) void fc_out_kernel(
    const unsigned int* __restrict__ h3pk, const float* __restrict__ Wo,
    const float* __restrict__ bo, float* __restrict__ q) {
  __shared__ float red[16][64];
  const int a  = blockIdx.x;
  const int bg = blockIdx.y;
  const int t  = threadIdx.x;
  const int bl = t & 63;
  const int ks = __builtin_amdgcn_readfirstlane(t >> 6);  // 0..15

  const unsigned int* __restrict__ hp =
      h3pk + (size_t)(ks * 32) * BB + bg * 64 + bl;
  const float* __restrict__ w = Wo + (size_t)a * HH + ks * 64;

  float acc = 0.f;
#pragma unroll 8
  for (int d = 0; d < 32; ++d) {
    const h2 hv = u2h(hp[(size_t)d * BB]);
    acc = fmaf((float)hv.x, w[2 * d], acc);
    acc = fmaf((float)hv.y, w[2 * d + 1], acc);
  }
  red[ks][bl] = acc;
  __syncthreads();

  if (t < 64) {
    float m = bo[a];
#pragma unroll
    for (int ks2 = 0; ks2 < 16; ++ks2) m += red[ks2][t];
    q[(size_t)(bg * 64 + t) * AA + a] = m;
  }
}

// ---------------------------------------------------------------------------
extern "C" void kernel_launch(void* const* d_in, const int* in_sizes, int n_in,
                              void* d_out, int out_size, void* d_ws, size_t ws_size,
                              hipStream_t stream) {
  const float* x    = (const float*)d_in[0];
  const float* Wi   = (const float*)d_in[1];
  const float* bi   = (const float*)d_in[2];
  const float* Wmax = (const float*)d_in[3];
  const float* Wmin = (const float*)d_in[4];
  const float* Wo   = (const float*)d_in[5];
  const float* bo   = (const float*)d_in[6];
  float* q = (float*)d_out;

  char* ws = (char*)d_ws;
  unsigned int* h1pk = (unsigned int*)ws;  ws += (size_t)(HH / 2) * BB * 4;  // 512 KB
  unsigned int* h2pk = (unsigned int*)ws;  ws += (size_t)(HH / 2) * BB * 4;
  unsigned int* h3pk = (unsigned int*)ws;

  fc_in_kernel<<<dim3(HH / 16, BB / 64), 1024, 0, stream>>>(x, Wi, bi, h1pk);
  mmplus_kernel<true ><<<dim3(HH / 8, BB / 64), 1024, 0, stream>>>(h1pk, Wmax, h2pk);
  mmplus_kernel<false><<<dim3(HH / 8, BB / 64), 1024, 0, stream>>>(h2pk, Wmin, h3pk);
  fc_out_kernel<<<dim3(AA, BB / 64), 1024, 0, stream>>>(h3pk, Wo, bo, q);
}

// Round 10
// 106.486 us; speedup vs baseline: 1.0061x; 1.0061x over previous
//
#include <hip/hip_runtime.h>
#include <math.h>

#define BB   256   // batch
#define OBS  256
#define HH   1024
#define AA   18

// clang-native packed f16: + -> v_pk_add_f16, elementwise_max -> v_pk_max_f16
typedef _Float16 h2 __attribute__((ext_vector_type(2)));

static __device__ __forceinline__ h2 u2h(unsigned int u) {
  return __builtin_bit_cast(h2, u);
}
static __device__ __forceinline__ unsigned int h2u(h2 v) {
  return __builtin_bit_cast(unsigned int, v);
}

// ---------------------------------------------------------------------------
// fc_in v3: h1pk[o/2][b] = pack_f16( x@W_in^T + b_in ) for o-pair
// grid (H/16, B/64), block 1024 = 8 k-splits x 2 o-octets. lane = b.
// KEY CHANGE vs R5/R8: W_in tile staged in LDS (16 o x 256 k f32, pitch 260
// for 16B-aligned b128 broadcast reads) instead of wave-uniform global
// pointers -> kills the 256-scalar-dword SMEM streaming serialization
// (same failure mode as R7's mmplus v2).
// x slice in LDS f32 (pitch 257, per-lane b32 reads, 2-way = free).
// ---------------------------------------------------------------------------
__global__ __launch_bounds__(1024) void fc_in_kernel(
    const float* __restrict__ x, const float* __restrict__ Wi,
    const float* __restrict__ bi, unsigned int* __restrict__ h1pk) {
  __shared__ float xs[64][OBS + 1];    // 65.8 KB
  __shared__ float ws_[16][260];       // 16.6 KB (pitch 260: 16B-aligned rows)
  __shared__ float red[8][16][64];     // 32 KB    (total ~112.5 KB)
  const int t    = threadIdx.x;
  const int lane = t & 63;
  const int wv   = __builtin_amdgcn_readfirstlane(t >> 6);
  const int oq   = wv & 1;
  const int s    = wv >> 1;        // k-split: 32 k each
  const int og   = blockIdx.x;
  const int bg   = blockIdx.y;
  const int k0   = s * 32;

  // ---- stage x slice (64 rows x 256 f32) ----
  {
    const int row = t >> 4;          // 0..63
    const int c4  = t & 15;          // 0..15
    const float4* src = (const float4*)(x + (size_t)(bg * 64 + row) * OBS);
#pragma unroll
    for (int k = 0; k < 4; ++k) {
      const float4 v = src[c4 + 16 * k];
      const int col = (c4 + 16 * k) * 4;
      xs[row][col]     = v.x;
      xs[row][col + 1] = v.y;
      xs[row][col + 2] = v.z;
      xs[row][col + 3] = v.w;
    }
  }
  // ---- stage W tile (16 rows x 256 f32): one wave per row, 1 float4/thread
  {
    const int row = wv;              // 0..15
    const int c   = lane;            // 0..63
    const float4 v =
        ((const float4*)(Wi + (size_t)(og * 16 + row) * OBS))[c];
    const int col = c * 4;
    ws_[row][col]     = v.x;
    ws_[row][col + 1] = v.y;
    ws_[row][col + 2] = v.z;
    ws_[row][col + 3] = v.w;
  }
  __syncthreads();

  const int ob = oq * 8;             // first block-local o of this wave
  float acc[8] = {0, 0, 0, 0, 0, 0, 0, 0};

#pragma unroll
  for (int k = 0; k < 32; k += 4) {
    const int kk = k0 + k;
    const float x0 = xs[lane][kk];
    const float x1 = xs[lane][kk + 1];
    const float x2 = xs[lane][kk + 2];
    const float x3 = xs[lane][kk + 3];
#pragma unroll
    for (int j = 0; j < 8; ++j) {
      const float4 w4 = *(const float4*)&ws_[ob + j][kk];  // broadcast b128
      acc[j] = fmaf(x0, w4.x, acc[j]);
      acc[j] = fmaf(x1, w4.y, acc[j]);
      acc[j] = fmaf(x2, w4.z, acc[j]);
      acc[j] = fmaf(x3, w4.w, acc[j]);
    }
  }

#pragma unroll
  for (int j = 0; j < 8; ++j) red[s][ob + j][lane] = acc[j];
  __syncthreads();

  if (t < 512) {
    const int op = t >> 6;           // block-local o-pair 0..7
    const int bl = t & 63;
    float s0 = 0.f, s1 = 0.f;
#pragma unroll
    for (int ks = 0; ks < 8; ++ks) {
      s0 += red[ks][2 * op][bl];
      s1 += red[ks][2 * op + 1][bl];
    }
    s0 += bi[og * 16 + 2 * op];
    s1 += bi[og * 16 + 2 * op + 1];
    h2 p = {(_Float16)s0, (_Float16)s1};
    h1pk[(size_t)(og * 8 + op) * BB + bg * 64 + bl] = h2u(p);
  }
}

// ---------------------------------------------------------------------------
// mmplus (R8 config — best measured): out[o][b] = OP_i( W[o][i] + h[i][b] )
// grid (H/8, B/64) = 512 blocks, block 1024 = 16 i-splits (64 i each).
// W f32 -> pk f16 into LDS in-flight (pitch 514, conflict-free b64 reads).
// Thread tile 2o x 4b. h coalesced dwordx4.
// ---------------------------------------------------------------------------
template <bool IS_MAX>
__global__ __launch_bounds__(1024) void mmplus_kernel(
    const unsigned int* __restrict__ hpk,   // [H/2][B] dwords (i-pair, b)
    const float* __restrict__ Wf,           // [H][H] f32 (o, i)
    unsigned int* __restrict__ opk) {       // [H/2][B]
  constexpr int PITCH = 514;
  __shared__ __align__(16) unsigned int lds[8 * PITCH];  // 16.4 KB; red aliases
  const int t    = threadIdx.x;
  const int lane = t & 63;
  const int og2  = lane >> 4;      // o-pair group 0..3
  const int bq   = lane & 15;      // b-quad 0..15
  const int s    = __builtin_amdgcn_readfirstlane(t >> 6);  // i-split 0..15
  const int og   = blockIdx.x;     // 0..127, 8 o each
  const int bg   = blockIdx.y;

  // ---- stage W tile: 8 rows (two waves per row), f32 -> pk f16 ----
  {
    const int o_l = t >> 7;        // 0..7
    const int c   = t & 127;
    const float4* src = (const float4*)(Wf + (size_t)(og * 8 + o_l) * HH);
    unsigned int* dst = &lds[o_l * PITCH];
#pragma unroll
    for (int k = 0; k < 2; ++k) {
      const float4 v = src[c + 128 * k];
      h2 p0 = {(_Float16)v.x, (_Float16)v.y};
      h2 p1 = {(_Float16)v.z, (_Float16)v.w};
      *(uint2*)&dst[(c + 128 * k) * 2] = make_uint2(h2u(p0), h2u(p1));
    }
  }
  __syncthreads();

  const unsigned int* __restrict__ hp =
      hpk + (size_t)(s * 32) * BB + bg * 64 + bq * 4;
  const _Float16 INIT = (_Float16)(IS_MAX ? -65504.f : 65504.f);
  h2 acc[2][4];
#pragma unroll
  for (int j = 0; j < 2; ++j)
#pragma unroll
    for (int bb = 0; bb < 4; ++bb) acc[j][bb] = (h2){INIT, INIT};

  // 32 i-pairs for this split, 2 pairs (4 i) per iteration
#pragma unroll 4
  for (int it = 0; it < 16; ++it) {
    const int p = it * 2;
    const uint4 h0 = *(const uint4*)(hp + (size_t)p * BB);
    const uint4 h1 = *(const uint4*)(hp + (size_t)(p + 1) * BB);
    const h2 h0v[4] = {u2h(h0.x), u2h(h0.y), u2h(h0.z), u2h(h0.w)};
    const h2 h1v[4] = {u2h(h1.x), u2h(h1.y), u2h(h1.z), u2h(h1.w)};
#pragma unroll
    for (int j = 0; j < 2; ++j) {
      const uint2 wj = *(const uint2*)&lds[(og2 * 2 + j) * PITCH + s * 32 + p];
      const h2 wa = u2h(wj.x);
      const h2 wb = u2h(wj.y);
#pragma unroll
      for (int bb = 0; bb < 4; ++bb) {
        if (IS_MAX) {
          acc[j][bb] = __builtin_elementwise_max(acc[j][bb], wa + h0v[bb]);
          acc[j][bb] = __builtin_elementwise_max(acc[j][bb], wb + h1v[bb]);
        } else {
          acc[j][bb] = __builtin_elementwise_min(acc[j][bb], wa + h0v[bb]);
          acc[j][bb] = __builtin_elementwise_min(acc[j][bb], wb + h1v[bb]);
        }
      }
    }
  }

  // fold even/odd i-partials -> scalar f16 per (o,b); pack this thread's
  // o-pair (j=0 even row, j=1 odd row)
  unsigned int opack[4];
#pragma unroll
  for (int bb = 0; bb < 4; ++bb) {
    const h2 ae = acc[0][bb], ao = acc[1][bb];
    const _Float16 me = IS_MAX ? (ae.x > ae.y ? ae.x : ae.y)
                               : (ae.x < ae.y ? ae.x : ae.y);
    const _Float16 mo = IS_MAX ? (ao.x > ao.y ? ao.x : ao.y)
                               : (ao.x < ao.y ? ao.x : ao.y);
    opack[bb] = h2u((h2){me, mo});
  }

  __syncthreads();  // W reads done; reuse lds[] as red[16][4][64] (16 KB)
#pragma unroll
  for (int bb = 0; bb < 4; ++bb)
    lds[s * 256 + og2 * 64 + bq * 4 + bb] = opack[bb];
  __syncthreads();

  if (t < 256) {
    const int op = t >> 6;   // o-pair 0..3
    const int bl = t & 63;
    h2 m = u2h(lds[op * 64 + bl]);
#pragma unroll
    for (int ks = 1; ks < 16; ++ks) {
      const h2 v = u2h(lds[ks * 256 + op * 64 + bl]);
      m = IS_MAX ? __builtin_elementwise_max(m, v)
                 : __builtin_elementwise_min(m, v);
    }
    opk[(size_t)(og * 4 + op) * BB + bg * 64 + bl] = h2u(m);
  }
}

// ---------------------------------------------------------------------------
// fc_out: q[b][a] = bo[a] + dot(h3[:,b], W_out[a,:])
// grid (A, B/64), block 1024 = 16 k-splits x 64 b. (64 scalar w-dwords per
// wave — fits SGPRs, no streaming issue.)
// ---------------------------------------------------------------------------
__global__ __launch_bounds__(1024) void fc_out_kernel(
    const unsigned int* __restrict__ h3pk, const float* __restrict__ Wo,
    const float* __restrict__ bo, float* __restrict__ q) {
  __shared__ float red[16][64];
  const int a  = blockIdx.x;
  const int bg = blockIdx.y;
  const int t  = threadIdx.x;
  const int bl = t & 63;
  const int ks = __builtin_amdgcn_readfirstlane(t >> 6);  // 0..15

  const unsigned int* __restrict__ hp =
      h3pk + (size_t)(ks * 32) * BB + bg * 64 + bl;
  const float* __restrict__ w = Wo + (size_t)a * HH + ks * 64;

  float acc = 0.f;
#pragma unroll 8
  for (int d = 0; d < 32; ++d) {
    const h2 hv = u2h(hp[(size_t)d * BB]);
    acc = fmaf((float)hv.x, w[2 * d], acc);
    acc = fmaf((float)hv.y, w[2 * d + 1], acc);
  }
  red[ks][bl] = acc;
  __syncthreads();

  if (t < 64) {
    float m = bo[a];
#pragma unroll
    for (int ks2 = 0; ks2 < 16; ++ks2) m += red[ks2][t];
    q[(size_t)(bg * 64 + t) * AA + a] = m;
  }
}

// ---------------------------------------------------------------------------
extern "C" void kernel_launch(void* const* d_in, const int* in_sizes, int n_in,
                              void* d_out, int out_size, void* d_ws, size_t ws_size,
                              hipStream_t stream) {
  const float* x    = (const float*)d_in[0];
  const float* Wi   = (const float*)d_in[1];
  const float* bi   = (const float*)d_in[2];
  const float* Wmax = (const float*)d_in[3];
  const float* Wmin = (const float*)d_in[4];
  const float* Wo   = (const float*)d_in[5];
  const float* bo   = (const float*)d_in[6];
  float* q = (float*)d_out;

  char* ws = (char*)d_ws;
  unsigned int* h1pk = (unsigned int*)ws;  ws += (size_t)(HH / 2) * BB * 4;  // 512 KB
  unsigned int* h2pk = (unsigned int*)ws;  ws += (size_t)(HH / 2) * BB * 4;
  unsigned int* h3pk = (unsigned int*)ws;

  fc_in_kernel<<<dim3(HH / 16, BB / 64), 1024, 0, stream>>>(x, Wi, bi, h1pk);
  mmplus_kernel<true ><<<dim3(HH / 8, BB / 64), 1024, 0, stream>>>(h1pk, Wmax, h2pk);
  mmplus_kernel<false><<<dim3(HH / 8, BB / 64), 1024, 0, stream>>>(h2pk, Wmin, h3pk);
  fc_out_kernel<<<dim3(AA, BB / 64), 1024, 0, stream>>>(h3pk, Wo, bo, q);
}